// Round 12
// baseline (47.197 us; speedup 1.0000x reference)
//
#include <hip/hip_runtime.h>

#define B_SZ 1024
#define F_SZ 512
#define NK   50
#define KD   5
#define C_SZ 250              // NK*KD
#define OUTW 562              // F_SZ + NK
#define PLANE (C_SZ * B_SZ)   // SoA M plane: [col c=k*5+d][row], 256000 floats
#define NT   16               // 16 row-tiles of 64
#define TILE 64
#define NPAIRS 136            // NT*(NT+1)/2 unordered tile pairs
#define PBLK  34              // tile pairs per block (4 waves x 34 blocks = 136)
#define PART_ELEMS (NK * NT * B_SZ)   // 819200 floats
#define LOG2E 1.44269504088896340736f

// ---------------------------------------------------------------------------
// K1: fused GEMM + copy (round-9 version, verbatim). grid 384 x 256.
//  blocks [0,256):   M = x@T scaled by log2e, SoA planes ws2[ks][c][row].
//                    rt = blk&127 (8 rows), ks = blk>>7 (256 f each).
//                    64 MB total T re-reads (L2/L3); x block-uniform -> s_load.
//  blocks [256,384): copy x rows into out (float2), 8 rows/block.
// ---------------------------------------------------------------------------
__global__ __launch_bounds__(256) void gemm_copy_kernel(const float* __restrict__ x,
                                                        const float* __restrict__ T,
                                                        float* __restrict__ ws2,
                                                        float* __restrict__ out,
                                                        int zero_feat) {
    const int t = threadIdx.x;

    if (blockIdx.x >= 256) {                 // ---- copy path
        const int b = blockIdx.x - 256;      // 0..127
#pragma unroll
        for (int r = 0; r < 8; ++r) {
            const int row = b * 8 + r;
            const float2* src = (const float2*)(x + (size_t)row * F_SZ);
            float2* dst = (float2*)(out + (size_t)row * OUTW);
            dst[t] = src[t];
            if (zero_feat && t < NK) out[(size_t)row * OUTW + F_SZ + t] = 0.0f;
        }
        return;
    }

    // ---- gemm path
    const int rt = blockIdx.x & 127;         // 8-row tile
    const int ks = blockIdx.x >> 7;          // k-split (0,1)
    if (t >= C_SZ) return;                   // no __syncthreads in this path
    const int r0 = rt * 8;
    const int f0 = ks * 256;

    float acc[8] = {0.f, 0.f, 0.f, 0.f, 0.f, 0.f, 0.f, 0.f};
    const float* xp = x + (size_t)r0 * F_SZ + f0;     // block-uniform base
    const float* Tp = T + (size_t)f0 * C_SZ + t;

#pragma unroll 8
    for (int f = 0; f < 256; ++f) {
        const float tv = Tp[(size_t)f * C_SZ];
#pragma unroll
        for (int r = 0; r < 8; ++r)
            acc[r] += xp[r * F_SZ + f] * tv;          // uniform -> s_load
    }

    float* dst = ws2 + ((size_t)(ks * C_SZ + t)) * B_SZ + r0;   // 32B aligned
    float4 lo = make_float4(acc[0] * LOG2E, acc[1] * LOG2E,
                            acc[2] * LOG2E, acc[3] * LOG2E);
    float4 hi = make_float4(acc[4] * LOG2E, acc[5] * LOG2E,
                            acc[6] * LOG2E, acc[7] * LOG2E);
    ((float4*)dst)[0] = lo;
    ((float4*)dst)[1] = hi;
}

// ---------------------------------------------------------------------------
// 64-lane DPP butterfly sum: returns total in lane 63 (AMD's canonical
// reduction: row_shr 1/2/4/8 with bound_ctrl=1, then row_bcast15 (row_mask
// 0xa) + row_bcast31 (row_mask 0xc); masked-off lanes contribute old=0).
// All VALU-pipe, no LDS.
// ---------------------------------------------------------------------------
__device__ __forceinline__ float dpp_sum64(float v) {
    int r = __float_as_int(v);
    int t;
    t = __builtin_amdgcn_update_dpp(0, r, 0x111, 0xf, 0xf, true);   // row_shr:1
    r = __float_as_int(__int_as_float(r) + __int_as_float(t));
    t = __builtin_amdgcn_update_dpp(0, r, 0x112, 0xf, 0xf, true);   // row_shr:2
    r = __float_as_int(__int_as_float(r) + __int_as_float(t));
    t = __builtin_amdgcn_update_dpp(0, r, 0x114, 0xf, 0xf, true);   // row_shr:4
    r = __float_as_int(__int_as_float(r) + __int_as_float(t));
    t = __builtin_amdgcn_update_dpp(0, r, 0x118, 0xf, 0xf, true);   // row_shr:8
    r = __float_as_int(__int_as_float(r) + __int_as_float(t));
    t = __builtin_amdgcn_update_dpp(0, r, 0x142, 0xa, 0xf, false);  // row_bcast15
    r = __float_as_int(__int_as_float(r) + __int_as_float(t));
    t = __builtin_amdgcn_update_dpp(0, r, 0x143, 0xc, 0xf, false);  // row_bcast31
    r = __float_as_int(__int_as_float(r) + __int_as_float(t));
    return __int_as_float(r);   // lane 63 = sum of all 64 lanes
}

// ---------------------------------------------------------------------------
// K2: symmetric pairwise features — ZERO LDS (round-10 lesson: pair was
// LDS-pipe-bound at ~19.5 us/CU; VALU had 3x headroom). grid 1700 = 50 k x
// 34 blocks; 256 threads = 4 waves, each wave owns ONE (ti,tj) tile pair.
//   - mi[d], mj[d] register-resident (10 coalesced L2-hit loads per wave).
//   - j-broadcast via v_readlane (VALU->SGPR) instead of ds_read_b128.
//   - column sums via DPP butterfly (VALU), then readlane(.,63) -> SGPR and
//     a predicated select deposits cs_j into lane j of vcol (v_cmp +
//     v_cndmask; no writelane builtin on this toolchain — round-11 lesson).
// Row partial -> part[k][tj][bi+lane]; col partial -> part[k][ti][bj+lane];
// each cell written by exactly one wave. Diagonal pairs: row pass only.
// NO atomics / fences / LDS on the fast path.
// ---------------------------------------------------------------------------
template <bool ATOMIC>
__global__ __launch_bounds__(256) void pair_kernel(const float* __restrict__ mp,
                                                   float* __restrict__ part,
                                                   float* __restrict__ out) {
    const int bid = blockIdx.x;
    const int k   = bid / PBLK;
    const int wv  = __builtin_amdgcn_readfirstlane(threadIdx.x >> 6);
    const int lane = threadIdx.x & 63;

    // decode pair index -> (ti, tj); scalar-uniform short loop
    int p = (bid - k * PBLK) * 4 + wv;       // 0..135
    int ti = 0;
    while (p >= NT - ti) { p -= NT - ti; ++ti; }
    const int tj = ti + p;
    const int bi = ti * TILE;
    const int bj = tj * TILE;
    const bool diag = (ti == tj);

    const float* pa = mp + (size_t)k * (KD * B_SZ);  // plane 0, cols k*5..
    const float* pb = pa + (size_t)PLANE;            // plane 1

    // register-resident tiles (sum the two k-split planes at load)
    float mi[KD], mj[KD];
#pragma unroll
    for (int d = 0; d < KD; ++d) {
        mi[d] = pa[d * B_SZ + bi + lane] + pb[d * B_SZ + bi + lane];
        mj[d] = pa[d * B_SZ + bj + lane] + pb[d * B_SZ + bj + lane];
    }

    float acci = 0.0f;       // row sums: i = bi+lane, summed over j in tj
    float vcol = 0.0f;       // lane j holds cs_j (col sum for row bj+j)

#pragma unroll
    for (int j = 0; j < TILE; ++j) {
        const float c0 = __int_as_float(__builtin_amdgcn_readlane(__float_as_int(mj[0]), j));
        const float c1 = __int_as_float(__builtin_amdgcn_readlane(__float_as_int(mj[1]), j));
        const float c2 = __int_as_float(__builtin_amdgcn_readlane(__float_as_int(mj[2]), j));
        const float c3 = __int_as_float(__builtin_amdgcn_readlane(__float_as_int(mj[3]), j));
        const float c4 = __int_as_float(__builtin_amdgcn_readlane(__float_as_int(mj[4]), j));
        const float s = __builtin_fabsf(mi[0] - c0)
                      + __builtin_fabsf(mi[1] - c1)
                      + __builtin_fabsf(mi[2] - c2)
                      + __builtin_fabsf(mi[3] - c3)
                      + __builtin_fabsf(mi[4] - c4);
        const float e = __builtin_amdgcn_exp2f(-s);
        acci += e;
        if (!diag) {                          // wave-uniform branch
            const float cs = dpp_sum64(e);    // lane 63 = column sum for this j
            const float csf = __int_as_float(
                __builtin_amdgcn_readlane(__float_as_int(cs), 63));  // -> SGPR
            vcol = (lane == j) ? csf : vcol;  // v_cmp + v_cndmask deposit
        }
    }

    // epilogue: coalesced per-wave stores (or atomic fallback)
    if (ATOMIC) {
        atomicAdd(&out[(size_t)(bi + lane) * OUTW + F_SZ + k], acci);
        if (!diag)
            atomicAdd(&out[(size_t)(bj + lane) * OUTW + F_SZ + k], vcol);
    } else {
        part[(size_t)(k * NT + tj) * B_SZ + bi + lane] = acci;
        if (!diag)
            part[(size_t)(k * NT + ti) * B_SZ + bj + lane] = vcol;
    }
}

// ---------------------------------------------------------------------------
// K3: fold the 16 tile-source partials into out. grid 200 x 256.
// Reads coalesced (lanes contiguous in row); L2-resident.
// ---------------------------------------------------------------------------
__global__ __launch_bounds__(256) void reduce_kernel(const float* __restrict__ part,
                                                     float* __restrict__ out) {
    const int k = blockIdx.x >> 2;
    const int i = ((blockIdx.x & 3) << 8) | threadIdx.x;
    float s = 0.0f;
#pragma unroll
    for (int sp = 0; sp < NT; ++sp)
        s += part[((size_t)(k * NT + sp)) * B_SZ + i];
    out[(size_t)i * OUTW + F_SZ + k] = s;
}

// ---------------------------------------------------------------------------
extern "C" void kernel_launch(void* const* d_in, const int* in_sizes, int n_in,
                              void* d_out, int out_size, void* d_ws, size_t ws_size,
                              hipStream_t stream) {
    const float* x = (const float*)d_in[0];   // [1024, 512]
    const float* T = (const float*)d_in[1];   // [512, 250]
    float* out = (float*)d_out;               // [1024, 562]
    float* ws2 = (float*)d_ws;                // 2 SoA planes [250][1024]
    float* part = ws2 + 2 * (size_t)PLANE;    // [50][16][1024]

    const size_t need = (size_t)(2 * PLANE + PART_ELEMS) * 4;   // 5.3 MB
    const int fast = (ws_size >= need);

    gemm_copy_kernel<<<384, 256, 0, stream>>>(x, T, ws2, out, fast ? 0 : 1);

    if (fast) {
        pair_kernel<false><<<NK * PBLK, 256, 0, stream>>>(ws2, part, out);
        reduce_kernel<<<200, 256, 0, stream>>>(part, out);
    } else {
        pair_kernel<true><<<NK * PBLK, 256, 0, stream>>>(ws2, nullptr, out);
    }
}

// Round 13
// 36.596 us; speedup vs baseline: 1.2897x; 1.2897x over previous
//
#include <hip/hip_runtime.h>

#define B_SZ 1024
#define F_SZ 512
#define NK   50
#define KD   5
#define C_SZ 250              // NK*KD
#define OUTW 562              // F_SZ + NK
#define PLANE (C_SZ * B_SZ)   // single summed SoA M plane: [c=k*5+d][row]
#define NT   16               // 16 row-tiles of 64
#define TILE 64
#define NPAIRS 136            // NT*(NT+1)/2 unordered tile pairs
#define PART_ELEMS (NK * NT * B_SZ)   // 819200 floats
#define LOG2E 1.44269504088896340736f

// ---------------------------------------------------------------------------
// K1: fused GEMM + copy. grid 384 x 256.
//  blocks [0,256):   M = x@T scaled by log2e -> SINGLE summed SoA plane
//                    mp[c][row] (pair's scalar j-side loads need one plane).
//                    4-row tiles, full K=512: T traffic 256x512KB = 128 MB
//                    (L2-resident slices; ~2us), x block-uniform -> s_loads.
//                    float4 store (r0 multiple of 4 -> 16B aligned).
//  blocks [256,384): copy x rows into out (float2), 8 rows/block.
// ---------------------------------------------------------------------------
__global__ __launch_bounds__(256) void gemm_copy_kernel(const float* __restrict__ x,
                                                        const float* __restrict__ T,
                                                        float* __restrict__ mp,
                                                        float* __restrict__ out,
                                                        int zero_feat) {
    const int t = threadIdx.x;

    if (blockIdx.x >= 256) {                 // ---- copy path
        const int b = blockIdx.x - 256;      // 0..127
#pragma unroll
        for (int r = 0; r < 8; ++r) {
            const int row = b * 8 + r;
            const float2* src = (const float2*)(x + (size_t)row * F_SZ);
            float2* dst = (float2*)(out + (size_t)row * OUTW);
            dst[t] = src[t];
            if (zero_feat && t < NK) out[(size_t)row * OUTW + F_SZ + t] = 0.0f;
        }
        return;
    }

    // ---- gemm path: 4-row tile, full K
    const int rt = blockIdx.x;               // 0..255
    if (t >= C_SZ) return;                   // no __syncthreads in this path
    const int r0 = rt * 4;

    float acc[4] = {0.f, 0.f, 0.f, 0.f};
    const float* xp = x + (size_t)r0 * F_SZ; // block-uniform base -> s_loads
    const float* Tp = T + t;

#pragma unroll 8
    for (int f = 0; f < F_SZ; ++f) {
        const float tv = Tp[(size_t)f * C_SZ];    // coalesced vector load
#pragma unroll
        for (int r = 0; r < 4; ++r)
            acc[r] += xp[r * F_SZ + f] * tv;      // uniform -> s_load
    }

    float4 v = make_float4(acc[0] * LOG2E, acc[1] * LOG2E,
                           acc[2] * LOG2E, acc[3] * LOG2E);
    *(float4*)(mp + (size_t)t * B_SZ + r0) = v;
}

// ---------------------------------------------------------------------------
// K2: symmetric pairwise features. grid 6800 = 50 k x 136 tile pairs (ti<=tj);
// 256 threads, jq = wave id (readfirstlane -> provably uniform).
// LDS budget halved vs round 9 (the working 35.7us base):
//   - j-side c-vectors: WAVE-UNIFORM global reads -> s_load_dwordx4 on the
//     scalar pipe (replaces 80 broadcast ds_read_b128/block, ~960cy of the
//     CU-shared LDS pipe). Round-12 lesson: DPP harvesting is 4x worse than
//     the et transpose; keep et in LDS for column sums.
//   - mi register-resident (coalesced global loads, no qi staging).
// pass 1: 16 pairs/thread (i=bi+lane, j=jq*16..+15); row sums in registers,
//         e stored to et[j][lane] (b32, skipped on diagonal blocks).
// pass 2: column sums = rows of et -> colp (off-diagonal only).
// Partials part[k][src_tile][row], each cell written by exactly one block.
// NO atomics / fences on the fast path.
// ---------------------------------------------------------------------------
template <bool ATOMIC>
__global__ __launch_bounds__(256) void pair_kernel(const float* __restrict__ mp,
                                                   float* __restrict__ part,
                                                   float* __restrict__ out) {
    // ---- decode block id -> (k, ti, tj), all scalar-uniform
    const int bid = blockIdx.x;
    const int k = bid / NPAIRS;
    int p = bid - k * NPAIRS;
    int ti = 0;
    while (p >= NT - ti) { p -= NT - ti; ++ti; }
    const int tj = ti + p;

    const int t    = threadIdx.x;
    const int lane = t & 63;
    const int jq   = __builtin_amdgcn_readfirstlane(t >> 6);   // wave-uniform

    __shared__ float et[TILE][TILE + 1];     // transpose harvest, b32 access
    __shared__ float rowp[4][TILE];
    __shared__ float colp[4][TILE];

    const float* pk = mp + (size_t)k * (KD * B_SZ);   // [5][1024] for this k
    const int bi = ti * TILE;
    const int bj = tj * TILE;
    const bool diag = (ti == tj);

    // i-side register-resident (coalesced vector loads, L2-hit)
    float mi[KD];
#pragma unroll
    for (int d = 0; d < KD; ++d) mi[d] = pk[d * B_SZ + bi + lane];

    float acci = 0.0f;
#pragma unroll
    for (int c4 = 0; c4 < 4; ++c4) {
        const int j0 = jq * 16 + c4 * 4;     // wave-uniform
        // uniform address -> s_load_dwordx4 (scalar pipe, zero LDS/VMEM)
        const float4 c0 = *(const float4*)(pk + 0 * B_SZ + bj + j0);
        const float4 c1 = *(const float4*)(pk + 1 * B_SZ + bj + j0);
        const float4 c2 = *(const float4*)(pk + 2 * B_SZ + bj + j0);
        const float4 c3 = *(const float4*)(pk + 3 * B_SZ + bj + j0);
        const float4 c4_ = *(const float4*)(pk + 4 * B_SZ + bj + j0);
#define PAIR_ONE(C, JOFF)                                                        \
        {                                                                        \
            const float s = __builtin_fabsf(mi[0] - c0.C)                        \
                          + __builtin_fabsf(mi[1] - c1.C)                        \
                          + __builtin_fabsf(mi[2] - c2.C)                        \
                          + __builtin_fabsf(mi[3] - c3.C)                        \
                          + __builtin_fabsf(mi[4] - c4_.C);                      \
            const float e = __builtin_amdgcn_exp2f(-s);                          \
            acci += e;                                                           \
            if (!diag) et[j0 + JOFF][lane] = e;                                  \
        }
        PAIR_ONE(x, 0) PAIR_ONE(y, 1) PAIR_ONE(z, 2) PAIR_ONE(w, 3)
#undef PAIR_ONE
    }
    rowp[jq][lane] = acci;
    __syncthreads();

    // ---- pass 2: column sums (rows of et), off-diagonal only
    if (!diag) {
        float csum = 0.0f;
#pragma unroll
        for (int e = 0; e < 16; ++e) csum += et[lane][jq * 16 + e];
        colp[jq][lane] = csum;
    }
    __syncthreads();

    // ---- epilogue: one coalesced store per 64-row strip
    if (t < TILE) {
        // rows of tile ti, source tile tj
        const float r = rowp[0][t] + rowp[1][t] + rowp[2][t] + rowp[3][t];
        if (ATOMIC) atomicAdd(&out[(size_t)(bi + t) * OUTW + F_SZ + k], r);
        else        part[(size_t)(k * NT + tj) * B_SZ + bi + t] = r;
    } else if (!diag && t < 2 * TILE) {
        // rows of tile tj, source tile ti
        const int l = t - TILE;
        const float c = colp[0][l] + colp[1][l] + colp[2][l] + colp[3][l];
        if (ATOMIC) atomicAdd(&out[(size_t)(bj + l) * OUTW + F_SZ + k], c);
        else        part[(size_t)(k * NT + ti) * B_SZ + bj + l] = c;
    }
}

// ---------------------------------------------------------------------------
// K3: fold the 16 tile-source partials into out. grid 200 x 256.
// Reads coalesced (lanes contiguous in row); L2-resident.
// ---------------------------------------------------------------------------
__global__ __launch_bounds__(256) void reduce_kernel(const float* __restrict__ part,
                                                     float* __restrict__ out) {
    const int k = blockIdx.x >> 2;
    const int i = ((blockIdx.x & 3) << 8) | threadIdx.x;
    float s = 0.0f;
#pragma unroll
    for (int sp = 0; sp < NT; ++sp)
        s += part[((size_t)(k * NT + sp)) * B_SZ + i];
    out[(size_t)i * OUTW + F_SZ + k] = s;
}

// ---------------------------------------------------------------------------
extern "C" void kernel_launch(void* const* d_in, const int* in_sizes, int n_in,
                              void* d_out, int out_size, void* d_ws, size_t ws_size,
                              hipStream_t stream) {
    const float* x = (const float*)d_in[0];   // [1024, 512]
    const float* T = (const float*)d_in[1];   // [512, 250]
    float* out = (float*)d_out;               // [1024, 562]
    float* mp  = (float*)d_ws;                // summed SoA plane [250][1024]
    float* part = mp + (size_t)PLANE;         // [50][16][1024]

    const size_t need = (size_t)(PLANE + PART_ELEMS) * 4;   // 4.3 MB
    const int fast = (ws_size >= need);

    gemm_copy_kernel<<<384, 256, 0, stream>>>(x, T, mp, out, fast ? 0 : 1);

    if (fast) {
        pair_kernel<false><<<NK * NPAIRS, 256, 0, stream>>>(mp, part, out);
        reduce_kernel<<<200, 256, 0, stream>>>(part, out);
    } else {
        pair_kernel<true><<<NK * NPAIRS, 256, 0, stream>>>(mp, nullptr, out);
    }
}